// Round 26
// baseline (611.313 us; speedup 1.0000x reference)
//
#include <hip/hip_runtime.h>
#include <hip/hip_bf16.h>

#define N_NODES 20000
#define E_EDGES 320000
#define HID 256
#define HEADS 4
#define CPH 64
#define LAYERS 3
#define NGRAPH 64
#define LN_EPS 1e-5f
#define NEG 0.2f
#define MAXD 256

__device__ __forceinline__ float lrelu_f(float v){ return v > 0.f ? v : NEG*v; }

// ---------------- edge decode ----------------
__global__ __launch_bounds__(256) void k_cvt_f(const int* __restrict__ raw,
                                               int* __restrict__ src, int* __restrict__ dst){
  int e = blockIdx.x*256 + threadIdx.x;
  if (e >= E_EDGES) return;
  src[e] = raw[e];
  dst[e] = raw[E_EDGES + e];
}

// ---------------- embed ----------------
__global__ __launch_bounds__(256) void k_embed_f(const float* __restrict__ x, const float* __restrict__ W,
                                                 const float* __restrict__ b, float* __restrict__ h){
  int n = blockIdx.x; int c = threadIdx.x;
  float x0 = x[n*3+0], x1 = x[n*3+1], x2 = x[n*3+2];
  h[(size_t)n*HID+c] = fmaf(x0, W[c], fmaf(x1, W[HID+c], fmaf(x2, W[2*HID+c], b[c])));
}

// ---------------- CSR build (by dst) ----------------
__global__ void k_hist_f(const int* __restrict__ dst, int* __restrict__ deg){
  int e = blockIdx.x*256 + threadIdx.x;
  if (e < E_EDGES) atomicAdd(&deg[dst[e]], 1);
}

__global__ __launch_bounds__(256) void k_scan_f(const int* __restrict__ deg, int* __restrict__ rp, int* __restrict__ cur){
  __shared__ int part[256];
  const int CH = (N_NODES + 255)/256;
  int t = threadIdx.x;
  int s = 0;
  for (int i=0;i<CH;i++){ int idx=t*CH+i; if (idx<N_NODES) s += deg[idx]; }
  part[t]=s; __syncthreads();
  for (int off=1; off<256; off<<=1){
    int v = (t>=off) ? part[t-off] : 0; __syncthreads();
    part[t]+=v; __syncthreads();
  }
  int run = (t==0) ? 0 : part[t-1];
  for (int i=0;i<CH;i++){ int idx=t*CH+i; if (idx<N_NODES){ rp[idx]=run; cur[idx]=run; run+=deg[idx]; } }
  if (t==255) rp[N_NODES]=run;
}

__global__ void k_scatter_f(const int* __restrict__ src, const int* __restrict__ dst, int* __restrict__ cur,
                            int* __restrict__ csrc){
  int e = blockIdx.x*256 + threadIdx.x;
  if (e < E_EDGES){
    int d = dst[e];
    int pos = atomicAdd(&cur[d],1);
    csrc[pos] = src[e];
  }
}

// ---------------- GEMM: C[M][256] = A[M][256] @ B[256][256] ----------------
__global__ __launch_bounds__(256) void k_gemm_f(const float* __restrict__ A, const float* __restrict__ B,
                                                float* __restrict__ C, int M){
  __shared__ float sA[64][68];
  __shared__ float sB[64][68];
  int r0 = blockIdx.x*64, c0 = blockIdx.y*64;
  int tid = threadIdx.x, tx = tid&15, ty = tid>>4;
  float acc[4][4] = {};
  for (int k0=0; k0<HID; k0+=64){
    #pragma unroll
    for (int i=0;i<4;i++){
      int slot = tid + i*256;
      int rr = slot>>4, kk = (slot&15)<<2;
      int gr = r0+rr; if (gr >= M) gr = M-1;
      float4 va = *(const float4*)(A + (size_t)gr*HID + k0 + kk);
      sA[kk+0][rr]=va.x; sA[kk+1][rr]=va.y; sA[kk+2][rr]=va.z; sA[kk+3][rr]=va.w;
      float4 vb = *(const float4*)(B + (size_t)(k0+rr)*HID + c0 + kk);
      sB[rr][kk+0]=vb.x; sB[rr][kk+1]=vb.y; sB[rr][kk+2]=vb.z; sB[rr][kk+3]=vb.w;
    }
    __syncthreads();
    #pragma unroll 8
    for (int k=0;k<64;k++){
      float4 a4 = *(const float4*)&sA[k][ty*4];
      float4 b4 = *(const float4*)&sB[k][tx*4];
      float av[4]={a4.x,a4.y,a4.z,a4.w}, bv[4]={b4.x,b4.y,b4.z,b4.w};
      #pragma unroll
      for (int i=0;i<4;i++)
        #pragma unroll
        for (int j=0;j<4;j++) acc[i][j] = fmaf(av[i], bv[j], acc[i][j]);
    }
    __syncthreads();
  }
  #pragma unroll
  for (int i=0;i<4;i++){
    int r = r0 + ty*4 + i;
    if (r < M){
      float4 o = {acc[i][0],acc[i][1],acc[i][2],acc[i][3]};
      *(float4*)(C + (size_t)r*HID + c0 + tx*4) = o;
    }
  }
}

// ---------------- per-node attention logits ----------------
__global__ __launch_bounds__(64) void k_alpha_f(const float* __restrict__ hp, const float* __restrict__ as_w,
                                                const float* __restrict__ ad_w,
                                                float* __restrict__ asn, float* __restrict__ adn){
  int n = blockIdx.x, lane = threadIdx.x;
  #pragma unroll
  for (int h=0; h<HEADS; h++){
    float v = hp[(size_t)n*HID + h*CPH + lane];
    float ps = v * as_w[h*CPH + lane];
    float pd = v * ad_w[h*CPH + lane];
    #pragma unroll
    for (int off=32; off; off>>=1){ ps += __shfl_xor(ps, off, 64); pd += __shfl_xor(pd, off, 64); }
    if (lane == 0){ asn[n*HEADS+h] = ps; adn[n*HEADS+h] = pd; }
  }
}

// ---------------- fused softmax-denominator + gather + bias + LayerNorm (4-wave, 256 threads) ----------------
// No max-subtraction (logits bounded); attn edge entries written by k_attn (edge-parallel).
__global__ __launch_bounds__(256) void k_aggr_f(const float* __restrict__ hp, const float* __restrict__ asn,
                                                const float* __restrict__ adn, const int* __restrict__ rp,
                                                const int* __restrict__ csrc,
                                                const float* __restrict__ bl, const float* __restrict__ lg,
                                                const float* __restrict__ lb, float* __restrict__ hout,
                                                float* __restrict__ invg, float* __restrict__ attn,
                                                float* __restrict__ hOut32){
  __shared__ float ps[MAXD][5];      // stride-5: bank-conflict-free
  __shared__ float pacc[4][256];
  __shared__ float wden[4][4];
  __shared__ float wsum[4], wsq[4];
  int n = blockIdx.x, t = threadIdx.x;
  int w = t>>6, l = t&63;
  int beg = rp[n];
  int cnt = rp[n+1] - beg;
  float ad[HEADS], slf[HEADS];
  #pragma unroll
  for (int h=0;h<HEADS;h++){
    ad[h]=adn[n*HEADS+h];
    slf[h]=__expf(lrelu_f(asn[n*HEADS+h]+ad[h]));  // appended self-loop weight
  }
  // phase 1: p per edge (256-thread parallel), den partials
  float dp[HEADS] = {0.f,0.f,0.f,0.f};
  for (int j=t; j<cnt; j+=256){
    int s = csrc[beg+j];
    #pragma unroll
    for (int h=0;h<HEADS;h++){
      float p = 0.f;
      if (s != n) p = __expf(lrelu_f(asn[s*HEADS+h]+ad[h]));
      if (j < MAXD) ps[j][h] = p;
      dp[h] += p;
    }
  }
  #pragma unroll
  for (int h=0;h<HEADS;h++){
    #pragma unroll
    for (int off=32; off; off>>=1) dp[h] += __shfl_xor(dp[h], off, 64);
  }
  if (l==0){
    #pragma unroll
    for (int h=0;h<HEADS;h++) wden[w][h]=dp[h];
  }
  __syncthreads();
  float inv[HEADS];
  #pragma unroll
  for (int h=0;h<HEADS;h++)
    inv[h] = 1.f / fmaxf(wden[0][h]+wden[1][h]+wden[2][h]+wden[3][h] + slf[h], 1e-16f);
  if (t==0){
    #pragma unroll
    for (int h=0;h<HEADS;h++){
      invg[n*HEADS+h] = inv[h];
      attn[(size_t)(E_EDGES+n)*HEADS + h] = slf[h]*inv[h];
    }
  }
  // phase 2: gather, edges split across 4 waves (chain length cnt/4)
  float acc[HEADS] = {0.f,0.f,0.f,0.f};
  for (int j=w; j<cnt; j+=4){
    int s = csrc[beg+j];
    if (j < MAXD){
      #pragma unroll
      for (int h=0;h<HEADS;h++)
        acc[h] = fmaf(ps[j][h], hp[(size_t)s*HID + h*CPH + l], acc[h]);
    } else if (s != n){
      #pragma unroll
      for (int h=0;h<HEADS;h++){
        float p = __expf(lrelu_f(asn[s*HEADS+h]+ad[h]));
        acc[h] = fmaf(p, hp[(size_t)s*HID + h*CPH + l], acc[h]);
      }
    }
  }
  if (w==0){
    #pragma unroll
    for (int h=0;h<HEADS;h++)
      acc[h] = fmaf(slf[h], hp[(size_t)n*HID + h*CPH + l], acc[h]);
  }
  #pragma unroll
  for (int h=0;h<HEADS;h++) pacc[w][h*CPH + l] = acc[h];
  __syncthreads();
  // channel c = t
  float o = (pacc[0][t]+pacc[1][t]+pacc[2][t]+pacc[3][t]) * inv[t>>6] + bl[t];
  // LN over 256 channels
  float sum = o, sq = o*o;
  #pragma unroll
  for (int off=32; off; off>>=1){ sum += __shfl_xor(sum,off,64); sq += __shfl_xor(sq,off,64); }
  if (l==0){ wsum[w]=sum; wsq[w]=sq; }
  __syncthreads();
  float S = wsum[0]+wsum[1]+wsum[2]+wsum[3];
  float Q = wsq[0]+wsq[1]+wsq[2]+wsq[3];
  float mu = S * (1.f/HID);
  float var = Q*(1.f/HID) - mu*mu;
  float rs = rsqrtf(var + LN_EPS);
  float y = (o-mu)*rs*lg[t] + lb[t];
  hout[(size_t)n*HID + t] = y;
  if (hOut32) hOut32[(size_t)n*HID + t] = y;
}

// ---------------- edge-parallel attn writer (coalesced float4 stores) ----------------
__global__ __launch_bounds__(256) void k_attn(const int* __restrict__ srcA, const int* __restrict__ dstA,
                                              const float* __restrict__ asn, const float* __restrict__ adn,
                                              const float* __restrict__ invg, float* __restrict__ attn){
  int e = blockIdx.x*256 + threadIdx.x;
  if (e >= E_EDGES) return;
  int s = srcA[e], d = dstA[e];
  float4 o;
  float* po = (float*)&o;
  #pragma unroll
  for (int h=0;h<HEADS;h++){
    float a = 0.f;
    if (s != d) a = __expf(lrelu_f(asn[s*HEADS+h]+adn[d*HEADS+h])) * invg[d*HEADS+h];
    po[h] = a;
  }
  *(float4*)(attn + (size_t)e*HEADS) = o;
}

// ---------------- two-stage mean pool ----------------
__global__ __launch_bounds__(256) void k_pool1(const float* __restrict__ h, const int* __restrict__ batch,
                                               float* __restrict__ gracc){
  const int nb = 2048;
  const int chunk = (N_NODES + nb - 1)/nb;
  int n0 = blockIdx.x*chunk;
  int n1 = n0 + chunk; if (n1 > N_NODES) n1 = N_NODES;
  if (n0 >= n1) return;
  int c = threadIdx.x;
  float acc = 0.f; int curg = -1;
  for (int n=n0; n<n1; ++n){
    int g = batch[n];
    if (g != curg){
      if (curg >= 0) atomicAdd(&gracc[curg*HID+c], acc);
      curg = g; acc = 0.f;
    }
    acc += h[(size_t)n*HID + c];
  }
  if (curg >= 0) atomicAdd(&gracc[curg*HID+c], acc);
}

__global__ __launch_bounds__(256) void k_pool2(const float* __restrict__ gracc, const int* __restrict__ batch,
                                               float* __restrict__ out_gr){
  int g = blockIdx.x, c = threadIdx.x;
  int lo=0, hi=N_NODES;
  while (lo<hi){ int mid=(lo+hi)>>1; if (batch[mid] < g) lo=mid+1; else hi=mid; }
  int start = lo;
  lo=start; hi=N_NODES;
  while (lo<hi){ int mid=(lo+hi)>>1; if (batch[mid] < g+1) lo=mid+1; else hi=mid; }
  float cnt = (float)(lo - start);
  out_gr[g*HID + c] = gracc[g*HID + c] / fmaxf(cnt, 1.f);
}

extern "C" void kernel_launch(void* const* d_in, const int* in_sizes, int n_in,
                              void* d_out, int out_size, void* d_ws, size_t ws_size,
                              hipStream_t stream){
  const float* x     = (const float*)d_in[0];
  const int*   ei    = (const int*)d_in[1];
  const int*   batch = (const int*)d_in[2];
  const float* W_emb = (const float*)d_in[3];
  const float* b_emb = (const float*)d_in[4];
  const float* W_gat = (const float*)d_in[5];
  const float* att_s = (const float*)d_in[6];
  const float* att_d = (const float*)d_in[7];
  const float* b_gat = (const float*)d_in[8];
  const float* ln_g  = (const float*)d_in[9];
  const float* ln_b  = (const float*)d_in[10];

  float* out     = (float*)d_out;
  float* out_h   = out;
  float* out_gr  = out + (size_t)N_NODES*HID;
  float* out_att = out_gr + (size_t)NGRAPH*HID;

  char* ws = (char*)d_ws;
  size_t off = 0;
  auto alloc = [&](size_t bytes){ void* p = ws + off; off += (bytes + 255) & ~size_t(255); return p; };
  float* h_cur = (float*)alloc((size_t)N_NODES*HID*4);
  float* hp    = (float*)alloc((size_t)N_NODES*HID*4);
  float* asn   = (float*)alloc((size_t)N_NODES*HEADS*4);
  float* adn   = (float*)alloc((size_t)N_NODES*HEADS*4);
  float* invg  = (float*)alloc((size_t)N_NODES*HEADS*4);
  int* deg     = (int*)alloc((size_t)N_NODES*4);
  int* rp      = (int*)alloc((size_t)(N_NODES+1)*4);
  int* cur     = (int*)alloc((size_t)N_NODES*4);
  int* csrc    = (int*)alloc((size_t)E_EDGES*4);
  int* srcA    = (int*)alloc((size_t)E_EDGES*4);
  int* dstA    = (int*)alloc((size_t)E_EDGES*4);
  float* gracc = (float*)alloc((size_t)NGRAPH*HID*4);

  hipMemsetAsync(deg, 0, (size_t)N_NODES*4, stream);
  hipMemsetAsync(gracc, 0, (size_t)NGRAPH*HID*4, stream);

  const int EG = (E_EDGES+255)/256;
  k_cvt_f    <<<EG, 256, 0, stream>>>(ei, srcA, dstA);
  k_hist_f   <<<EG, 256, 0, stream>>>(dstA, deg);
  k_scan_f   <<<1, 256, 0, stream>>>(deg, rp, cur);
  k_scatter_f<<<EG, 256, 0, stream>>>(srcA, dstA, cur, csrc);

  k_embed_f  <<<N_NODES, 256, 0, stream>>>(x, W_emb, b_emb, h_cur);

  dim3 ggrid((N_NODES+63)/64, HID/64);
  for (int l=0; l<LAYERS; ++l){
    float* attn_l = out_att + (size_t)l*(E_EDGES+N_NODES)*HEADS;
    k_gemm_f <<<ggrid, 256, 0, stream>>>(h_cur, W_gat + (size_t)l*HID*HID, hp, N_NODES);
    k_alpha_f<<<N_NODES, 64, 0, stream>>>(hp, att_s + l*HEADS*CPH, att_d + l*HEADS*CPH, asn, adn);
    k_aggr_f <<<N_NODES, 256, 0, stream>>>(hp, asn, adn, rp, csrc,
              b_gat + l*HID, ln_g + l*HID, ln_b + l*HID, h_cur,
              invg, attn_l,
              (l==LAYERS-1) ? out_h : (float*)nullptr);
    k_attn   <<<EG, 256, 0, stream>>>(srcA, dstA, asn, adn, invg, attn_l);
  }
  k_pool1<<<2048, 256, 0, stream>>>(h_cur, batch, gracc);
  k_pool2<<<NGRAPH, 256, 0, stream>>>(gracc, batch, out_gr);
}

// Round 27
// 510.028 us; speedup vs baseline: 1.1986x; 1.1986x over previous
//
#include <hip/hip_runtime.h>
#include <hip/hip_bf16.h>

#define N_NODES 20000
#define E_EDGES 320000
#define HID 256
#define HEADS 4
#define CPH 64
#define LAYERS 3
#define NGRAPH 64
#define LN_EPS 1e-5f
#define NEG 0.2f
#define MAXD 256

__device__ __forceinline__ float lrelu_f(float v){ return v > 0.f ? v : NEG*v; }

// ---------------- edge decode ----------------
__global__ __launch_bounds__(256) void k_cvt_f(const int* __restrict__ raw,
                                               int* __restrict__ src, int* __restrict__ dst){
  int e = blockIdx.x*256 + threadIdx.x;
  if (e >= E_EDGES) return;
  src[e] = raw[e];
  dst[e] = raw[E_EDGES + e];
}

// ---------------- embed (writes fp32 + bf16 copy) ----------------
__global__ __launch_bounds__(256) void k_embed_f(const float* __restrict__ x, const float* __restrict__ W,
                                                 const float* __restrict__ b, float* __restrict__ h){
  int n = blockIdx.x; int c = threadIdx.x;
  float x0 = x[n*3+0], x1 = x[n*3+1], x2 = x[n*3+2];
  h[(size_t)n*HID+c] = fmaf(x0, W[c], fmaf(x1, W[HID+c], fmaf(x2, W[2*HID+c], b[c])));
}

// ---------------- CSR build (by dst) ----------------
__global__ void k_hist_f(const int* __restrict__ dst, int* __restrict__ deg){
  int e = blockIdx.x*256 + threadIdx.x;
  if (e < E_EDGES) atomicAdd(&deg[dst[e]], 1);
}

__global__ __launch_bounds__(256) void k_scan_f(const int* __restrict__ deg, int* __restrict__ rp, int* __restrict__ cur){
  __shared__ int part[256];
  const int CH = (N_NODES + 255)/256;
  int t = threadIdx.x;
  int s = 0;
  for (int i=0;i<CH;i++){ int idx=t*CH+i; if (idx<N_NODES) s += deg[idx]; }
  part[t]=s; __syncthreads();
  for (int off=1; off<256; off<<=1){
    int v = (t>=off) ? part[t-off] : 0; __syncthreads();
    part[t]+=v; __syncthreads();
  }
  int run = (t==0) ? 0 : part[t-1];
  for (int i=0;i<CH;i++){ int idx=t*CH+i; if (idx<N_NODES){ rp[idx]=run; cur[idx]=run; run+=deg[idx]; } }
  if (t==255) rp[N_NODES]=run;
}

__global__ void k_scatter_f(const int* __restrict__ src, const int* __restrict__ dst, int* __restrict__ cur,
                            int* __restrict__ csrc){
  int e = blockIdx.x*256 + threadIdx.x;
  if (e < E_EDGES){
    int d = dst[e];
    int pos = atomicAdd(&cur[d],1);
    csrc[pos] = src[e];
  }
}

// ---------------- GEMM: C = A @ B ; epilogue also emits bf16 copy of C ----------------
__global__ __launch_bounds__(256) void k_gemm_f(const float* __restrict__ A, const float* __restrict__ B,
                                                float* __restrict__ C, __hip_bfloat16* __restrict__ C16,
                                                int M){
  __shared__ float sA[64][68];
  __shared__ float sB[64][68];
  int r0 = blockIdx.x*64, c0 = blockIdx.y*64;
  int tid = threadIdx.x, tx = tid&15, ty = tid>>4;
  float acc[4][4] = {};
  for (int k0=0; k0<HID; k0+=64){
    #pragma unroll
    for (int i=0;i<4;i++){
      int slot = tid + i*256;
      int rr = slot>>4, kk = (slot&15)<<2;
      int gr = r0+rr; if (gr >= M) gr = M-1;
      float4 va = *(const float4*)(A + (size_t)gr*HID + k0 + kk);
      sA[kk+0][rr]=va.x; sA[kk+1][rr]=va.y; sA[kk+2][rr]=va.z; sA[kk+3][rr]=va.w;
      float4 vb = *(const float4*)(B + (size_t)(k0+rr)*HID + c0 + kk);
      sB[rr][kk+0]=vb.x; sB[rr][kk+1]=vb.y; sB[rr][kk+2]=vb.z; sB[rr][kk+3]=vb.w;
    }
    __syncthreads();
    #pragma unroll 8
    for (int k=0;k<64;k++){
      float4 a4 = *(const float4*)&sA[k][ty*4];
      float4 b4 = *(const float4*)&sB[k][tx*4];
      float av[4]={a4.x,a4.y,a4.z,a4.w}, bv[4]={b4.x,b4.y,b4.z,b4.w};
      #pragma unroll
      for (int i=0;i<4;i++)
        #pragma unroll
        for (int j=0;j<4;j++) acc[i][j] = fmaf(av[i], bv[j], acc[i][j]);
    }
    __syncthreads();
  }
  #pragma unroll
  for (int i=0;i<4;i++){
    int r = r0 + ty*4 + i;
    if (r < M){
      float4 o = {acc[i][0],acc[i][1],acc[i][2],acc[i][3]};
      *(float4*)(C + (size_t)r*HID + c0 + tx*4) = o;
      __hip_bfloat16 b0=__float2bfloat16(acc[i][0]), b1=__float2bfloat16(acc[i][1]),
                     b2=__float2bfloat16(acc[i][2]), b3=__float2bfloat16(acc[i][3]);
      ushort4 o16 = { *(unsigned short*)&b0, *(unsigned short*)&b1,
                      *(unsigned short*)&b2, *(unsigned short*)&b3 };
      *(ushort4*)((unsigned short*)C16 + (size_t)r*HID + c0 + tx*4) = o16;
    }
  }
}

// ---------------- per-node attention logits ----------------
__global__ __launch_bounds__(64) void k_alpha_f(const float* __restrict__ hp, const float* __restrict__ as_w,
                                                const float* __restrict__ ad_w,
                                                float* __restrict__ asn, float* __restrict__ adn){
  int n = blockIdx.x, lane = threadIdx.x;
  #pragma unroll
  for (int h=0; h<HEADS; h++){
    float v = hp[(size_t)n*HID + h*CPH + lane];
    float ps = v * as_w[h*CPH + lane];
    float pd = v * ad_w[h*CPH + lane];
    #pragma unroll
    for (int off=32; off; off>>=1){ ps += __shfl_xor(ps, off, 64); pd += __shfl_xor(pd, off, 64); }
    if (lane == 0){ asn[n*HEADS+h] = ps; adn[n*HEADS+h] = pd; }
  }
}

// ---------------- fused softmax-denom + bf16 gather + bias + LayerNorm (64-thread, r25 structure) ----------------
__global__ __launch_bounds__(64) void k_aggr_f(const __hip_bfloat16* __restrict__ hp16,
                                               const float* __restrict__ hp,
                                               const float* __restrict__ asn,
                                               const float* __restrict__ adn, const int* __restrict__ rp,
                                               const int* __restrict__ csrc,
                                               const float* __restrict__ bl, const float* __restrict__ lg,
                                               const float* __restrict__ lb, float* __restrict__ hout,
                                               float* __restrict__ invg, float* __restrict__ attn,
                                               float* __restrict__ hOut32){
  __shared__ float ps[MAXD][5];           // stride-5: conflict-free
  int n = blockIdx.x, lane = threadIdx.x;
  int beg = rp[n];
  int cnt = rp[n+1] - beg;
  float ad[HEADS], slf[HEADS];
  #pragma unroll
  for (int h=0;h<HEADS;h++){
    ad[h]=adn[n*HEADS+h];
    slf[h]=__expf(lrelu_f(asn[n*HEADS+h]+ad[h]));
  }
  // phase 1: lane-parallel p per edge, den partials
  float dp[HEADS] = {0.f,0.f,0.f,0.f};
  for (int j=lane; j<cnt; j+=64){
    int s = csrc[beg+j];
    #pragma unroll
    for (int h=0;h<HEADS;h++){
      float p = 0.f;
      if (s != n) p = __expf(lrelu_f(asn[s*HEADS+h]+ad[h]));
      if (j < MAXD) ps[j][h] = p;
      dp[h] += p;
    }
  }
  #pragma unroll
  for (int h=0;h<HEADS;h++){
    #pragma unroll
    for (int off=32; off; off>>=1) dp[h] += __shfl_xor(dp[h], off, 64);
  }
  float inv[HEADS];
  #pragma unroll
  for (int h=0;h<HEADS;h++) inv[h] = 1.f / fmaxf(dp[h] + slf[h], 1e-16f);
  if (lane==0){
    #pragma unroll
    for (int h=0;h<HEADS;h++){
      invg[n*HEADS+h] = inv[h];
      attn[(size_t)(E_EDGES+n)*HEADS + h] = slf[h]*inv[h];
    }
  }
  __syncthreads();
  // phase 2: weighted gather of bf16 hp rows
  float acc[HEADS];
  #pragma unroll
  for (int h=0;h<HEADS;h++) acc[h] = slf[h]*hp[(size_t)n*HID + h*CPH + lane];
  for (int j=0;j<cnt;j++){
    int s = csrc[beg+j];
    if (j < MAXD){
      #pragma unroll
      for (int h=0;h<HEADS;h++)
        acc[h] = fmaf(ps[j][h], __bfloat162float(hp16[(size_t)s*HID + h*CPH + lane]), acc[h]);
    } else if (s != n){
      #pragma unroll
      for (int h=0;h<HEADS;h++){
        float p = __expf(lrelu_f(asn[s*HEADS+h]+ad[h]));
        acc[h] = fmaf(p, __bfloat162float(hp16[(size_t)s*HID + h*CPH + lane]), acc[h]);
      }
    }
  }
  float o[HEADS], sum=0.f, sq=0.f;
  #pragma unroll
  for (int h=0;h<HEADS;h++){
    o[h] = fmaf(acc[h], inv[h], bl[h*CPH+lane]);
    sum += o[h]; sq = fmaf(o[h],o[h],sq);
  }
  #pragma unroll
  for (int off=32; off; off>>=1){ sum += __shfl_xor(sum,off,64); sq += __shfl_xor(sq,off,64); }
  float mu = sum * (1.f/HID);
  float var = sq*(1.f/HID) - mu*mu;
  float rs = rsqrtf(var + LN_EPS);
  #pragma unroll
  for (int h=0;h<HEADS;h++){
    int c = h*CPH+lane;
    float y = (o[h]-mu)*rs*lg[c] + lb[c];
    hout[(size_t)n*HID + c] = y;
    if (hOut32) hOut32[(size_t)n*HID + c] = y;
  }
}

// ---------------- edge-parallel attn writer (coalesced float4 stores) ----------------
__global__ __launch_bounds__(256) void k_attn(const int* __restrict__ srcA, const int* __restrict__ dstA,
                                              const float* __restrict__ asn, const float* __restrict__ adn,
                                              const float* __restrict__ invg, float* __restrict__ attn){
  int e = blockIdx.x*256 + threadIdx.x;
  if (e >= E_EDGES) return;
  int s = srcA[e], d = dstA[e];
  float4 o;
  float* po = (float*)&o;
  #pragma unroll
  for (int h=0;h<HEADS;h++){
    float a = 0.f;
    if (s != d) a = __expf(lrelu_f(asn[s*HEADS+h]+adn[d*HEADS+h])) * invg[d*HEADS+h];
    po[h] = a;
  }
  *(float4*)(attn + (size_t)e*HEADS) = o;
}

// ---------------- two-stage mean pool ----------------
__global__ __launch_bounds__(256) void k_pool1(const float* __restrict__ h, const int* __restrict__ batch,
                                               float* __restrict__ gracc){
  const int nb = 2048;
  const int chunk = (N_NODES + nb - 1)/nb;
  int n0 = blockIdx.x*chunk;
  int n1 = n0 + chunk; if (n1 > N_NODES) n1 = N_NODES;
  if (n0 >= n1) return;
  int c = threadIdx.x;
  float acc = 0.f; int curg = -1;
  for (int n=n0; n<n1; ++n){
    int g = batch[n];
    if (g != curg){
      if (curg >= 0) atomicAdd(&gracc[curg*HID+c], acc);
      curg = g; acc = 0.f;
    }
    acc += h[(size_t)n*HID + c];
  }
  if (curg >= 0) atomicAdd(&gracc[curg*HID+c], acc);
}

__global__ __launch_bounds__(256) void k_pool2(const float* __restrict__ gracc, const int* __restrict__ batch,
                                               float* __restrict__ out_gr){
  int g = blockIdx.x, c = threadIdx.x;
  int lo=0, hi=N_NODES;
  while (lo<hi){ int mid=(lo+hi)>>1; if (batch[mid] < g) lo=mid+1; else hi=mid; }
  int start = lo;
  lo=start; hi=N_NODES;
  while (lo<hi){ int mid=(lo+hi)>>1; if (batch[mid] < g+1) lo=mid+1; else hi=mid; }
  float cnt = (float)(lo - start);
  out_gr[g*HID + c] = gracc[g*HID + c] / fmaxf(cnt, 1.f);
}

extern "C" void kernel_launch(void* const* d_in, const int* in_sizes, int n_in,
                              void* d_out, int out_size, void* d_ws, size_t ws_size,
                              hipStream_t stream){
  const float* x     = (const float*)d_in[0];
  const int*   ei    = (const int*)d_in[1];
  const int*   batch = (const int*)d_in[2];
  const float* W_emb = (const float*)d_in[3];
  const float* b_emb = (const float*)d_in[4];
  const float* W_gat = (const float*)d_in[5];
  const float* att_s = (const float*)d_in[6];
  const float* att_d = (const float*)d_in[7];
  const float* b_gat = (const float*)d_in[8];
  const float* ln_g  = (const float*)d_in[9];
  const float* ln_b  = (const float*)d_in[10];

  float* out     = (float*)d_out;
  float* out_h   = out;
  float* out_gr  = out + (size_t)N_NODES*HID;
  float* out_att = out_gr + (size_t)NGRAPH*HID;

  char* ws = (char*)d_ws;
  size_t off = 0;
  auto alloc = [&](size_t bytes){ void* p = ws + off; off += (bytes + 255) & ~size_t(255); return p; };
  float* h_cur = (float*)alloc((size_t)N_NODES*HID*4);
  float* hp    = (float*)alloc((size_t)N_NODES*HID*4);
  __hip_bfloat16* hp16 = (__hip_bfloat16*)alloc((size_t)N_NODES*HID*2);
  float* asn   = (float*)alloc((size_t)N_NODES*HEADS*4);
  float* adn   = (float*)alloc((size_t)N_NODES*HEADS*4);
  float* invg  = (float*)alloc((size_t)N_NODES*HEADS*4);
  int* deg     = (int*)alloc((size_t)N_NODES*4);
  int* rp      = (int*)alloc((size_t)(N_NODES+1)*4);
  int* cur     = (int*)alloc((size_t)N_NODES*4);
  int* csrc    = (int*)alloc((size_t)E_EDGES*4);
  int* srcA    = (int*)alloc((size_t)E_EDGES*4);
  int* dstA    = (int*)alloc((size_t)E_EDGES*4);
  float* gracc = (float*)alloc((size_t)NGRAPH*HID*4);

  hipMemsetAsync(deg, 0, (size_t)N_NODES*4, stream);
  hipMemsetAsync(gracc, 0, (size_t)NGRAPH*HID*4, stream);

  const int EG = (E_EDGES+255)/256;
  k_cvt_f    <<<EG, 256, 0, stream>>>(ei, srcA, dstA);
  k_hist_f   <<<EG, 256, 0, stream>>>(dstA, deg);
  k_scan_f   <<<1, 256, 0, stream>>>(deg, rp, cur);
  k_scatter_f<<<EG, 256, 0, stream>>>(srcA, dstA, cur, csrc);

  k_embed_f  <<<N_NODES, 256, 0, stream>>>(x, W_emb, b_emb, h_cur);

  dim3 ggrid((N_NODES+63)/64, HID/64);
  for (int l=0; l<LAYERS; ++l){
    float* attn_l = out_att + (size_t)l*(E_EDGES+N_NODES)*HEADS;
    k_gemm_f <<<ggrid, 256, 0, stream>>>(h_cur, W_gat + (size_t)l*HID*HID, hp, hp16, N_NODES);
    k_alpha_f<<<N_NODES, 64, 0, stream>>>(hp, att_s + l*HEADS*CPH, att_d + l*HEADS*CPH, asn, adn);
    k_aggr_f <<<N_NODES, 64, 0, stream>>>(hp16, hp, asn, adn, rp, csrc,
              b_gat + l*HID, ln_g + l*HID, ln_b + l*HID, h_cur,
              invg, attn_l,
              (l==LAYERS-1) ? out_h : (float*)nullptr);
    k_attn   <<<EG, 256, 0, stream>>>(srcA, dstA, asn, adn, invg, attn_l);
  }
  k_pool1<<<2048, 256, 0, stream>>>(h_cur, batch, gracc);
  k_pool2<<<NGRAPH, 256, 0, stream>>>(gracc, batch, out_gr);
}

// Round 28
// 475.638 us; speedup vs baseline: 1.2852x; 1.0723x over previous
//
#include <hip/hip_runtime.h>
#include <hip/hip_bf16.h>

#define N_NODES 20000
#define E_EDGES 320000
#define HID 256
#define HEADS 4
#define CPH 64
#define LAYERS 3
#define NGRAPH 64
#define LN_EPS 1e-5f
#define NEG 0.2f
#define MAXD 256

__device__ __forceinline__ float lrelu_f(float v){ return v > 0.f ? v : NEG*v; }

// ---------------- edge decode ----------------
__global__ __launch_bounds__(256) void k_cvt_f(const int* __restrict__ raw,
                                               int* __restrict__ src, int* __restrict__ dst){
  int e = blockIdx.x*256 + threadIdx.x;
  if (e >= E_EDGES) return;
  src[e] = raw[e];
  dst[e] = raw[E_EDGES + e];
}

// ---------------- embed ----------------
__global__ __launch_bounds__(256) void k_embed_f(const float* __restrict__ x, const float* __restrict__ W,
                                                 const float* __restrict__ b, float* __restrict__ h){
  int n = blockIdx.x; int c = threadIdx.x;
  float x0 = x[n*3+0], x1 = x[n*3+1], x2 = x[n*3+2];
  h[(size_t)n*HID+c] = fmaf(x0, W[c], fmaf(x1, W[HID+c], fmaf(x2, W[2*HID+c], b[c])));
}

// ---------------- CSR build (by dst) ----------------
__global__ void k_hist_f(const int* __restrict__ dst, int* __restrict__ deg){
  int e = blockIdx.x*256 + threadIdx.x;
  if (e < E_EDGES) atomicAdd(&deg[dst[e]], 1);
}

__global__ __launch_bounds__(256) void k_scan_f(const int* __restrict__ deg, int* __restrict__ rp, int* __restrict__ cur){
  __shared__ int part[256];
  const int CH = (N_NODES + 255)/256;
  int t = threadIdx.x;
  int s = 0;
  for (int i=0;i<CH;i++){ int idx=t*CH+i; if (idx<N_NODES) s += deg[idx]; }
  part[t]=s; __syncthreads();
  for (int off=1; off<256; off<<=1){
    int v = (t>=off) ? part[t-off] : 0; __syncthreads();
    part[t]+=v; __syncthreads();
  }
  int run = (t==0) ? 0 : part[t-1];
  for (int i=0;i<CH;i++){ int idx=t*CH+i; if (idx<N_NODES){ rp[idx]=run; cur[idx]=run; run+=deg[idx]; } }
  if (t==255) rp[N_NODES]=run;
}

__global__ void k_scatter_f(const int* __restrict__ src, const int* __restrict__ dst, int* __restrict__ cur,
                            int* __restrict__ csrc){
  int e = blockIdx.x*256 + threadIdx.x;
  if (e < E_EDGES){
    int d = dst[e];
    int pos = atomicAdd(&cur[d],1);
    csrc[pos] = src[e];
  }
}

// ---------------- GEMM: hp16 = bf16(A @ B), alpha logits fused in epilogue ----------------
// Block (bx, by): rows bx*64.., cols by*64.. = exactly head `by`.
__global__ __launch_bounds__(256) void k_gemm_f(const float* __restrict__ A, const float* __restrict__ B,
                                                __hip_bfloat16* __restrict__ C16,
                                                const float* __restrict__ as_w, const float* __restrict__ ad_w,
                                                float* __restrict__ asn, float* __restrict__ adn,
                                                int M){
  __shared__ float sA[64][68];
  __shared__ float sB[64][68];
  int r0 = blockIdx.x*64, c0 = blockIdx.y*64;
  int head = blockIdx.y;
  int tid = threadIdx.x, tx = tid&15, ty = tid>>4;
  float acc[4][4] = {};
  for (int k0=0; k0<HID; k0+=64){
    #pragma unroll
    for (int i=0;i<4;i++){
      int slot = tid + i*256;
      int rr = slot>>4, kk = (slot&15)<<2;
      int gr = r0+rr; if (gr >= M) gr = M-1;
      float4 va = *(const float4*)(A + (size_t)gr*HID + k0 + kk);
      sA[kk+0][rr]=va.x; sA[kk+1][rr]=va.y; sA[kk+2][rr]=va.z; sA[kk+3][rr]=va.w;
      float4 vb = *(const float4*)(B + (size_t)(k0+rr)*HID + c0 + kk);
      sB[rr][kk+0]=vb.x; sB[rr][kk+1]=vb.y; sB[rr][kk+2]=vb.z; sB[rr][kk+3]=vb.w;
    }
    __syncthreads();
    #pragma unroll 8
    for (int k=0;k<64;k++){
      float4 a4 = *(const float4*)&sA[k][ty*4];
      float4 b4 = *(const float4*)&sB[k][tx*4];
      float av[4]={a4.x,a4.y,a4.z,a4.w}, bv[4]={b4.x,b4.y,b4.z,b4.w};
      #pragma unroll
      for (int i=0;i<4;i++)
        #pragma unroll
        for (int j=0;j<4;j++) acc[i][j] = fmaf(av[i], bv[j], acc[i][j]);
    }
    __syncthreads();
  }
  #pragma unroll
  for (int i=0;i<4;i++){
    int r = r0 + ty*4 + i;
    bool valid = (r < M);
    if (valid){
      __hip_bfloat16 b0=__float2bfloat16(acc[i][0]), b1=__float2bfloat16(acc[i][1]),
                     b2=__float2bfloat16(acc[i][2]), b3=__float2bfloat16(acc[i][3]);
      ushort4 o16 = { *(unsigned short*)&b0, *(unsigned short*)&b1,
                      *(unsigned short*)&b2, *(unsigned short*)&b3 };
      *(ushort4*)((unsigned short*)C16 + (size_t)r*HID + c0 + tx*4) = o16;
    }
    // fused alpha partial: dot(acc_row, att[c0..c0+64)) reduced over the 16 tx lanes
    float pa = 0.f, pd = 0.f;
    #pragma unroll
    for (int j=0;j<4;j++){
      int c = c0 + tx*4 + j;
      pa = fmaf(acc[i][j], as_w[c], pa);
      pd = fmaf(acc[i][j], ad_w[c], pd);
    }
    #pragma unroll
    for (int off=1; off<16; off<<=1){ pa += __shfl_xor(pa, off, 64); pd += __shfl_xor(pd, off, 64); }
    if (valid && tx == 0){
      asn[r*HEADS + head] = pa;
      adn[r*HEADS + head] = pd;
    }
  }
}

// ---------------- fused softmax-denom + bf16 gather + bias + LayerNorm ----------------
__global__ __launch_bounds__(64) void k_aggr_f(const __hip_bfloat16* __restrict__ hp16,
                                               const float* __restrict__ asn,
                                               const float* __restrict__ adn, const int* __restrict__ rp,
                                               const int* __restrict__ csrc,
                                               const float* __restrict__ bl, const float* __restrict__ lg,
                                               const float* __restrict__ lb, float* __restrict__ hout,
                                               float* __restrict__ invg, float* __restrict__ attn,
                                               float* __restrict__ hOut32){
  __shared__ float ps[MAXD][5];           // stride-5: conflict-free
  int n = blockIdx.x, lane = threadIdx.x;
  int beg = rp[n];
  int cnt = rp[n+1] - beg;
  float ad[HEADS], slf[HEADS];
  #pragma unroll
  for (int h=0;h<HEADS;h++){
    ad[h]=adn[n*HEADS+h];
    slf[h]=__expf(lrelu_f(asn[n*HEADS+h]+ad[h]));
  }
  float dp[HEADS] = {0.f,0.f,0.f,0.f};
  for (int j=lane; j<cnt; j+=64){
    int s = csrc[beg+j];
    #pragma unroll
    for (int h=0;h<HEADS;h++){
      float p = 0.f;
      if (s != n) p = __expf(lrelu_f(asn[s*HEADS+h]+ad[h]));
      if (j < MAXD) ps[j][h] = p;
      dp[h] += p;
    }
  }
  #pragma unroll
  for (int h=0;h<HEADS;h++){
    #pragma unroll
    for (int off=32; off; off>>=1) dp[h] += __shfl_xor(dp[h], off, 64);
  }
  float inv[HEADS];
  #pragma unroll
  for (int h=0;h<HEADS;h++) inv[h] = 1.f / fmaxf(dp[h] + slf[h], 1e-16f);
  if (lane==0){
    #pragma unroll
    for (int h=0;h<HEADS;h++){
      invg[n*HEADS+h] = inv[h];
      attn[(size_t)(E_EDGES+n)*HEADS + h] = slf[h]*inv[h];
    }
  }
  __syncthreads();
  // gather (all bf16)
  float acc[HEADS];
  #pragma unroll
  for (int h=0;h<HEADS;h++)
    acc[h] = slf[h]*__bfloat162float(hp16[(size_t)n*HID + h*CPH + lane]);
  for (int j=0;j<cnt;j++){
    int s = csrc[beg+j];
    if (j < MAXD){
      #pragma unroll
      for (int h=0;h<HEADS;h++)
        acc[h] = fmaf(ps[j][h], __bfloat162float(hp16[(size_t)s*HID + h*CPH + lane]), acc[h]);
    } else if (s != n){
      #pragma unroll
      for (int h=0;h<HEADS;h++){
        float p = __expf(lrelu_f(asn[s*HEADS+h]+ad[h]));
        acc[h] = fmaf(p, __bfloat162float(hp16[(size_t)s*HID + h*CPH + lane]), acc[h]);
      }
    }
  }
  float o[HEADS], sum=0.f, sq=0.f;
  #pragma unroll
  for (int h=0;h<HEADS;h++){
    o[h] = fmaf(acc[h], inv[h], bl[h*CPH+lane]);
    sum += o[h]; sq = fmaf(o[h],o[h],sq);
  }
  #pragma unroll
  for (int off=32; off; off>>=1){ sum += __shfl_xor(sum,off,64); sq += __shfl_xor(sq,off,64); }
  float mu = sum * (1.f/HID);
  float var = sq*(1.f/HID) - mu*mu;
  float rs = rsqrtf(var + LN_EPS);
  #pragma unroll
  for (int h=0;h<HEADS;h++){
    int c = h*CPH+lane;
    float y = (o[h]-mu)*rs*lg[c] + lb[c];
    hout[(size_t)n*HID + c] = y;
    if (hOut32) hOut32[(size_t)n*HID + c] = y;
  }
}

// ---------------- edge-parallel attn writer (coalesced float4 stores) ----------------
__global__ __launch_bounds__(256) void k_attn(const int* __restrict__ srcA, const int* __restrict__ dstA,
                                              const float* __restrict__ asn, const float* __restrict__ adn,
                                              const float* __restrict__ invg, float* __restrict__ attn){
  int e = blockIdx.x*256 + threadIdx.x;
  if (e >= E_EDGES) return;
  int s = srcA[e], d = dstA[e];
  float4 o;
  float* po = (float*)&o;
  #pragma unroll
  for (int h=0;h<HEADS;h++){
    float a = 0.f;
    if (s != d) a = __expf(lrelu_f(asn[s*HEADS+h]+adn[d*HEADS+h])) * invg[d*HEADS+h];
    po[h] = a;
  }
  *(float4*)(attn + (size_t)e*HEADS) = o;
}

// ---------------- two-stage mean pool ----------------
__global__ __launch_bounds__(256) void k_pool1(const float* __restrict__ h, const int* __restrict__ batch,
                                               float* __restrict__ gracc){
  const int nb = 2048;
  const int chunk = (N_NODES + nb - 1)/nb;
  int n0 = blockIdx.x*chunk;
  int n1 = n0 + chunk; if (n1 > N_NODES) n1 = N_NODES;
  if (n0 >= n1) return;
  int c = threadIdx.x;
  float acc = 0.f; int curg = -1;
  for (int n=n0; n<n1; ++n){
    int g = batch[n];
    if (g != curg){
      if (curg >= 0) atomicAdd(&gracc[curg*HID+c], acc);
      curg = g; acc = 0.f;
    }
    acc += h[(size_t)n*HID + c];
  }
  if (curg >= 0) atomicAdd(&gracc[curg*HID+c], acc);
}

__global__ __launch_bounds__(256) void k_pool2(const float* __restrict__ gracc, const int* __restrict__ batch,
                                               float* __restrict__ out_gr){
  int g = blockIdx.x, c = threadIdx.x;
  int lo=0, hi=N_NODES;
  while (lo<hi){ int mid=(lo+hi)>>1; if (batch[mid] < g) lo=mid+1; else hi=mid; }
  int start = lo;
  lo=start; hi=N_NODES;
  while (lo<hi){ int mid=(lo+hi)>>1; if (batch[mid] < g+1) lo=mid+1; else hi=mid; }
  float cnt = (float)(lo - start);
  out_gr[g*HID + c] = gracc[g*HID + c] / fmaxf(cnt, 1.f);
}

extern "C" void kernel_launch(void* const* d_in, const int* in_sizes, int n_in,
                              void* d_out, int out_size, void* d_ws, size_t ws_size,
                              hipStream_t stream){
  const float* x     = (const float*)d_in[0];
  const int*   ei    = (const int*)d_in[1];
  const int*   batch = (const int*)d_in[2];
  const float* W_emb = (const float*)d_in[3];
  const float* b_emb = (const float*)d_in[4];
  const float* W_gat = (const float*)d_in[5];
  const float* att_s = (const float*)d_in[6];
  const float* att_d = (const float*)d_in[7];
  const float* b_gat = (const float*)d_in[8];
  const float* ln_g  = (const float*)d_in[9];
  const float* ln_b  = (const float*)d_in[10];

  float* out     = (float*)d_out;
  float* out_h   = out;
  float* out_gr  = out + (size_t)N_NODES*HID;
  float* out_att = out_gr + (size_t)NGRAPH*HID;

  char* ws = (char*)d_ws;
  size_t off = 0;
  auto alloc = [&](size_t bytes){ void* p = ws + off; off += (bytes + 255) & ~size_t(255); return p; };
  float* h_cur = (float*)alloc((size_t)N_NODES*HID*4);
  __hip_bfloat16* hp16 = (__hip_bfloat16*)alloc((size_t)N_NODES*HID*2);
  float* asn   = (float*)alloc((size_t)N_NODES*HEADS*4);
  float* adn   = (float*)alloc((size_t)N_NODES*HEADS*4);
  float* invg  = (float*)alloc((size_t)N_NODES*HEADS*4);
  int* deg     = (int*)alloc((size_t)N_NODES*4);
  int* rp      = (int*)alloc((size_t)(N_NODES+1)*4);
  int* cur     = (int*)alloc((size_t)N_NODES*4);
  int* csrc    = (int*)alloc((size_t)E_EDGES*4);
  int* srcA    = (int*)alloc((size_t)E_EDGES*4);
  int* dstA    = (int*)alloc((size_t)E_EDGES*4);
  float* gracc = (float*)alloc((size_t)NGRAPH*HID*4);

  hipMemsetAsync(deg, 0, (size_t)N_NODES*4, stream);
  hipMemsetAsync(gracc, 0, (size_t)NGRAPH*HID*4, stream);

  const int EG = (E_EDGES+255)/256;
  k_cvt_f    <<<EG, 256, 0, stream>>>(ei, srcA, dstA);
  k_hist_f   <<<EG, 256, 0, stream>>>(dstA, deg);
  k_scan_f   <<<1, 256, 0, stream>>>(deg, rp, cur);
  k_scatter_f<<<EG, 256, 0, stream>>>(srcA, dstA, cur, csrc);

  k_embed_f  <<<N_NODES, 256, 0, stream>>>(x, W_emb, b_emb, h_cur);

  dim3 ggrid((N_NODES+63)/64, HID/64);
  for (int l=0; l<LAYERS; ++l){
    float* attn_l = out_att + (size_t)l*(E_EDGES+N_NODES)*HEADS;
    k_gemm_f <<<ggrid, 256, 0, stream>>>(h_cur, W_gat + (size_t)l*HID*HID, hp16,
                                         att_s + l*HEADS*CPH, att_d + l*HEADS*CPH,
                                         asn, adn, N_NODES);
    k_aggr_f <<<N_NODES, 64, 0, stream>>>(hp16, asn, adn, rp, csrc,
              b_gat + l*HID, ln_g + l*HID, ln_b + l*HID, h_cur,
              invg, attn_l,
              (l==LAYERS-1) ? out_h : (float*)nullptr);
    k_attn   <<<EG, 256, 0, stream>>>(srcA, dstA, asn, adn, invg, attn_l);
  }
  k_pool1<<<2048, 256, 0, stream>>>(h_cur, batch, gracc);
  k_pool2<<<NGRAPH, 256, 0, stream>>>(gracc, batch, out_gr);
}